// Round 1
// baseline (430.578 us; speedup 1.0000x reference)
//
#include <hip/hip_runtime.h>

// Problem constants (x: 512x3x224x224 fp32, W: 768 fp32, b: 1 fp32, P=16)
constexpr int BATCH   = 512;
constexpr int CHW     = 150528;   // 3*224*224 per batch
constexpr int CPLANE  = 50176;    // 224*224
constexpr int OUT_PB  = 196;      // outputs per batch (150528/768)
constexpr int ROWLEN  = 768;      // C*P*P
constexpr int SLAB    = 588;      // C*Hn*Wn = 3*14*14 (per (p1,p2))
constexpr int SLABP   = 589;      // padded LDS stride (589 % 32 = 13, odd -> spread)
constexpr int BLOCK_O = 9408;     // 16*588: o-range per (b,p1) block
constexpr int NF4     = 2352;     // 9408/4 float4 loads per block

__global__ __launch_bounds__(256) void init_out_kernel(float* __restrict__ out,
                                                       const float* __restrict__ bias,
                                                       int n) {
    int i = blockIdx.x * 256 + threadIdx.x;
    if (i < n) out[i] = bias[0];
}

__global__ __launch_bounds__(256) void patch_score_kernel(const float* __restrict__ x,
                                                          const float* __restrict__ W,
                                                          float* __restrict__ out) {
    __shared__ float lds[16 * SLABP];   // 9424 floats = 37,696 B

    const int b   = blockIdx.x >> 4;
    const int p1  = blockIdx.x & 15;
    const int tid = threadIdx.x;

    // ---- Phase 1: coalesced load of 42 rows (c in [0,3), h in [0,14), row 16h+p1),
    // scatter into LDS at u' = p2*589 + (c*196 + h*14 + w)  [u = p2*588 + t, pad +p2]
    const float* __restrict__ xb = x + (size_t)b * CHW;
    for (int f = tid; f < NF4; f += 256) {
        const int seg = f / 56;           // c*14 + h   (56 float4 per 224-float row)
        const int off = f - seg * 56;
        const int c = seg / 14;
        const int h = seg - c * 14;
        const float4 v = *(const float4*)(xb + c * CPLANE + (16 * h + p1) * 224 + 4 * off);
        const int t_base = c * 196 + h * 14;
        const float vv[4] = {v.x, v.y, v.z, v.w};
#pragma unroll
        for (int e = 0; e < 4; ++e) {
            const int ww = 4 * off + e;
            const int p2 = ww & 15;
            const int w  = ww >> 4;
            lds[p2 * SLABP + t_base + w] = vv[e];
        }
    }
    __syncthreads();

    // ---- Phase 2: per-wave dot products for the 13-14 output rows this block touches.
    const int lane = tid & 63;
    const int wv   = tid >> 6;

    // Weight index for (j, i, lane) is k = i*64+lane, independent of j -> registers.
    float wreg[12];
#pragma unroll
    for (int i = 0; i < 12; ++i) wreg[i] = W[i * 64 + lane];

    const int o_base  = p1 * BLOCK_O;
    const int j_start = o_base / ROWLEN;
    const int j_end   = (o_base + BLOCK_O - 1) / ROWLEN;

    for (int j = j_start + wv; j <= j_end; j += 4) {
        float acc = 0.0f;
        const int kb = j * ROWLEN - o_base;   // u for k=0 (may be negative at low edge)
#pragma unroll
        for (int i = 0; i < 12; ++i) {
            const int u = kb + i * 64 + lane;
            if (u >= 0 && u < BLOCK_O) {
                const unsigned uu = (unsigned)u;
                acc += lds[uu + uu / 588u] * wreg[i];   // uu/588 == p2 -> padded addr
            }
        }
#pragma unroll
        for (int off = 32; off > 0; off >>= 1)
            acc += __shfl_down(acc, off, 64);
        if (lane == 0) atomicAdd(&out[b * OUT_PB + j], acc);
    }
}

extern "C" void kernel_launch(void* const* d_in, const int* in_sizes, int n_in,
                              void* d_out, int out_size, void* d_ws, size_t ws_size,
                              hipStream_t stream) {
    const float* x    = (const float*)d_in[0];
    const float* W    = (const float*)d_in[1];
    const float* bias = (const float*)d_in[2];
    float* out = (float*)d_out;

    // out = bias everywhere (d_out is poisoned before every call)
    init_out_kernel<<<(out_size + 255) / 256, 256, 0, stream>>>(out, bias, out_size);

    // one block per (batch, p1): 512*16 = 8192 blocks
    patch_score_kernel<<<BATCH * 16, 256, 0, stream>>>(x, W, out);
}

// Round 2
// 406.394 us; speedup vs baseline: 1.0595x; 1.0595x over previous
//
#include <hip/hip_runtime.h>

// Problem constants (x: 512x3x224x224 fp32, W: 768 fp32, b: 1 fp32, P=16)
constexpr int BATCH   = 512;
constexpr int CHW     = 150528;   // 3*224*224 per batch
constexpr int CPLANE  = 50176;    // 224*224
constexpr int OUT_PB  = 196;      // outputs per batch (150528/768)
constexpr int ROWLEN  = 768;      // C*P*P
constexpr int SLABP   = 589;      // padded LDS stride (589 % 32 = 13 -> banks spread)
constexpr int BLOCK_O = 9408;     // 16*588: o-range per (b,p1) block
constexpr int NF4     = 2352;     // 9408/4 float4 loads per block

__global__ __launch_bounds__(256) void init_out_kernel(float* __restrict__ out,
                                                       const float* __restrict__ bias,
                                                       int n) {
    int i = blockIdx.x * 256 + threadIdx.x;
    if (i < n) out[i] = bias[0];
}

__global__ __launch_bounds__(256) void patch_score_kernel(const float* __restrict__ x,
                                                          const float* __restrict__ W,
                                                          float* __restrict__ out) {
    __shared__ float lds[16 * SLABP];   // 9424 floats = 37,696 B -> 4 blocks/CU

    const int b   = blockIdx.x >> 4;
    const int p1  = blockIdx.x & 15;
    const int tid = threadIdx.x;

    const float* __restrict__ xb = x + (size_t)b * CHW;

    // ---- Phase 1a: issue ALL global loads first (9 unconditional + 1 predicated
    // per thread) so 9-10 float4 loads are in flight per thread -> latency hidden.
    float4 r[9];
#pragma unroll
    for (int i = 0; i < 9; ++i) {
        const int f   = tid + i * 256;        // f < 2304 always
        const int seg = f / 56;               // c*14 + h
        const int off = f - seg * 56;
        const int c   = seg / 14;
        const int h   = seg - c * 14;
        r[i] = *(const float4*)(xb + c * CPLANE + (16 * h + p1) * 224 + 4 * off);
    }
    float4 r9;
    if (tid < 48) {                           // f = 2304+tid -> seg=41 (c=2,h=13), off=tid+8
        r9 = *(const float4*)(xb + 2 * CPLANE + (16 * 13 + p1) * 224 + 4 * (tid + 8));
    }

    // ---- Phase 1b: scatter into LDS at p2*589 + (c*196 + h*14 + w), ww=4*off+e,
    // p2 = ww & 15, w = ww >> 4.
#pragma unroll
    for (int i = 0; i < 9; ++i) {
        const int f      = tid + i * 256;
        const int seg    = f / 56;
        const int off    = f - seg * 56;
        const int c      = seg / 14;
        const int h      = seg - c * 14;
        const int t_base = c * 196 + h * 14;
        const float vv[4] = {r[i].x, r[i].y, r[i].z, r[i].w};
#pragma unroll
        for (int e = 0; e < 4; ++e) {
            const int ww = 4 * off + e;
            lds[(ww & 15) * SLABP + t_base + (ww >> 4)] = vv[e];
        }
    }
    if (tid < 48) {
        const int off    = tid + 8;
        const int t_base = 2 * 196 + 13 * 14;
        const float vv[4] = {r9.x, r9.y, r9.z, r9.w};
#pragma unroll
        for (int e = 0; e < 4; ++e) {
            const int ww = 4 * off + e;
            lds[(ww & 15) * SLABP + t_base + (ww >> 4)] = vv[e];
        }
    }
    __syncthreads();

    // ---- Phase 2: per-wave dot products for the 13-14 output rows this block touches.
    const int lane = tid & 63;
    const int wv   = tid >> 6;

    float wreg[12];
#pragma unroll
    for (int i = 0; i < 12; ++i) wreg[i] = W[i * 64 + lane];

    const int o_base  = p1 * BLOCK_O;
    const int j_start = o_base / ROWLEN;
    const int j_end   = (o_base + BLOCK_O - 1) / ROWLEN;

    for (int j = j_start + wv; j <= j_end; j += 4) {
        float acc = 0.0f;
        const int kb = j * ROWLEN - o_base;   // u for k=0 (may be negative at low edge)
#pragma unroll
        for (int i = 0; i < 12; ++i) {
            const int u = kb + i * 64 + lane;
            if (u >= 0 && u < BLOCK_O) {
                const unsigned uu = (unsigned)u;
                acc += lds[uu + uu / 588u] * wreg[i];   // uu/588 == p2 -> padded addr
            }
        }
#pragma unroll
        for (int off = 32; off > 0; off >>= 1)
            acc += __shfl_down(acc, off, 64);
        if (lane == 0) atomicAdd(&out[b * OUT_PB + j], acc);
    }
}

extern "C" void kernel_launch(void* const* d_in, const int* in_sizes, int n_in,
                              void* d_out, int out_size, void* d_ws, size_t ws_size,
                              hipStream_t stream) {
    const float* x    = (const float*)d_in[0];
    const float* W    = (const float*)d_in[1];
    const float* bias = (const float*)d_in[2];
    float* out = (float*)d_out;

    // out = bias everywhere (d_out is poisoned before every call)
    init_out_kernel<<<(out_size + 255) / 256, 256, 0, stream>>>(out, bias, out_size);

    // one block per (batch, p1): 512*16 = 8192 blocks
    patch_score_kernel<<<BATCH * 16, 256, 0, stream>>>(x, W, out);
}